// Round 10
// baseline (764.843 us; speedup 1.0000x reference)
//
#include <hip/hip_runtime.h>

// ---- problem dims (fixed) ----
#define T_TOK 8192      // B*S
#define DMODEL 1024
#define NEXP 8
#define TOPK 2
#define HID 4096
#define NPAIR (T_TOK*TOPK)   // 16384
#define BM 256
#define BN 256
#define BK 64
#define MAXT (NPAIR/BM + NEXP)    // 72 (256-row tiles)
#define MAXT2 (NPAIR/128 + NEXP)  // 136 (128-row tiles)

typedef unsigned short u16;
typedef unsigned int u32;
typedef short s16x8 __attribute__((ext_vector_type(8)));
typedef float f32x4 __attribute__((ext_vector_type(4)));

// fp32 -> bf16 round-to-nearest-even
__device__ __forceinline__ u16 f2b(float f) {
    union { float f; unsigned int u; } v; v.f = f;
    return (u16)((v.u + 0x7fffu + ((v.u >> 16) & 1u)) >> 16);
}

__device__ __forceinline__ s16x8 cvt8(float4 f0, float4 f1) {
    s16x8 o;
    o[0]=(short)f2b(f0.x); o[1]=(short)f2b(f0.y); o[2]=(short)f2b(f0.z); o[3]=(short)f2b(f0.w);
    o[4]=(short)f2b(f1.x); o[5]=(short)f2b(f1.y); o[6]=(short)f2b(f1.z); o[7]=(short)f2b(f1.w);
    return o;
}

// async global->LDS, 16B per lane; LDS dest linear in lane order
__device__ __forceinline__ void gload16(const void* g, void* l) {
    __builtin_amdgcn_global_load_lds(
        (const __attribute__((address_space(1))) unsigned int*)g,
        (__attribute__((address_space(3))) unsigned int*)l, 16, 0, 0);
}

// tanh-form gelu, exp/rcp in HW
__device__ __forceinline__ float gelu_fast(float v) {
    float y = 0.7978845608028654f * v * fmaf(0.044715f * v, v, 1.0f);
    float t = -2.8853900817779268f * y;   // -2y * log2(e)
    float z, r;
    asm("v_exp_f32 %0, %1" : "=v"(z) : "v"(t));
    float den = 1.0f + z;
    asm("v_rcp_f32 %0, %1" : "=v"(r) : "v"(den));
    return v * r;
}

// ---------------- fp32 -> bf16 conversion ----------------
__global__ __launch_bounds__(256) void cvt_kernel(const float* __restrict__ in,
                                                  u16* __restrict__ out, long n8) {
    long stride = (long)gridDim.x * 256;
    for (long i = (long)blockIdx.x * 256 + threadIdx.x; i < n8; i += stride) {
        const float4* p = (const float4*)(in + i * 8);
        float4 f0 = p[0], f1 = p[1];
        *(s16x8*)(out + i * 8) = cvt8(f0, f1);
    }
}

// ---------------- router (fp32; selection must match reference) ----------------
__global__ __launch_bounds__(256) void router_kernel(
    const float* __restrict__ x, const float* __restrict__ Wr, const float* __restrict__ br,
    int* __restrict__ topi, float* __restrict__ topw, int* __restrict__ cnt)
{
    __shared__ float WrS[NEXP * DMODEL];
    int tid = threadIdx.x;
    const float4* Wr4 = (const float4*)Wr;
    float4* WrS4 = (float4*)WrS;
    for (int i = tid; i < NEXP * DMODEL / 4; i += 256) WrS4[i] = Wr4[i];
    __syncthreads();

    int wid = tid >> 6, lane = tid & 63;
    int t = blockIdx.x * 4 + wid;
    const float* xr = x + (size_t)t * DMODEL;

    float acc[NEXP];
#pragma unroll
    for (int e = 0; e < NEXP; ++e) acc[e] = 0.f;
    for (int i = lane; i < DMODEL; i += 64) {
        float xv = xr[i];
#pragma unroll
        for (int e = 0; e < NEXP; ++e) acc[e] = fmaf(xv, WrS[e * DMODEL + i], acc[e]);
    }
#pragma unroll
    for (int e = 0; e < NEXP; ++e) {
        float v = acc[e];
#pragma unroll
        for (int off = 32; off > 0; off >>= 1) v += __shfl_xor(v, off);
        acc[e] = v;
    }
    if (lane == 0) {
        float lg[NEXP];
#pragma unroll
        for (int e = 0; e < NEXP; ++e) lg[e] = acc[e] + br[e];
        int i1 = 0;
#pragma unroll
        for (int e = 1; e < NEXP; ++e) if (lg[e] > lg[i1]) i1 = e;
        int i2 = (i1 == 0) ? 1 : 0;
#pragma unroll
        for (int e = 0; e < NEXP; ++e) if (e != i1 && lg[e] > lg[i2]) i2 = e;
        float e2 = expf(lg[i2] - lg[i1]);
        float s = 1.f + e2;
        topi[t * 2] = i1;  topi[t * 2 + 1] = i2;
        topw[t * 2] = 1.f / s;  topw[t * 2 + 1] = e2 / s;
        atomicAdd(&cnt[i1], 1);
        atomicAdd(&cnt[i2], 1);
    }
}

// offsets + tile tables (256-row for gemm1, 128-row for gemm2) + counts
__global__ void offsets_kernel(const int* __restrict__ cnt, int* __restrict__ offs,
                               u32* __restrict__ table, u32* __restrict__ table2,
                               int* __restrict__ meta) {
    if (threadIdx.x == 0 && blockIdx.x == 0) {
        int a = 0;
        for (int e = 0; e < NEXP; ++e) { offs[e] = a; a += cnt[e]; }
        offs[NEXP] = a;
        int nt = 0;
        for (int e = 0; e < NEXP; ++e)
            for (int r0 = 0; r0 < cnt[e]; r0 += BM)
                table[nt++] = ((u32)e << 20) | (u32)r0;
        meta[0] = nt;
        int nt2 = 0;
        for (int e = 0; e < NEXP; ++e)
            for (int r0 = 0; r0 < cnt[e]; r0 += 128)
                table2[nt2++] = ((u32)e << 20) | (u32)r0;
        meta[1] = nt2;
    }
}

// wave-aggregated scatter
__global__ __launch_bounds__(256) void scatter_kernel(
    const int* __restrict__ topi, const float* __restrict__ topw,
    const int* __restrict__ offs, int* __restrict__ fill,
    int* __restrict__ tok, float* __restrict__ wgt)
{
    int t = blockIdx.x * 256 + threadIdx.x;
    int lane = threadIdx.x & 63;
#pragma unroll
    for (int s = 0; s < TOPK; ++s) {
        int e = topi[t * 2 + s];
        float w = topw[t * 2 + s];
#pragma unroll
        for (int ex = 0; ex < NEXP; ++ex) {
            unsigned long long m = __ballot(e == ex);
            if (e == ex) {
                int ldr = (int)__ffsll((unsigned long long)m) - 1;
                int base = 0;
                if (lane == ldr) base = atomicAdd(&fill[ex], (int)__popcll(m));
                base = __shfl(base, ldr);
                int mypos = base + (int)__popcll(m & ((1ull << lane) - 1ull));
                int p = offs[ex] + mypos;
                tok[p] = t;
                wgt[p] = w;
            }
        }
    }
}

#define BARX() do { __builtin_amdgcn_s_barrier(); asm volatile("" ::: "memory"); } while (0)
#define VM8() asm volatile("s_waitcnt vmcnt(8)" ::: "memory")
#define VM6() asm volatile("s_waitcnt vmcnt(6)" ::: "memory")
#define VM0() asm volatile("s_waitcnt vmcnt(0)" ::: "memory")

// ================= gemm1: 256x256 core (R9 structure, new XCD mapping) ======
#define LDS_A(c, h)  ((char*)S + (c) * 65536 + (h) * 16384)
#define LDS_B(c, kk) ((char*)S + (c) * 65536 + 32768 + (kk) * 16384)

#define STG_A(dst, o0, o1, koff) do {                                       \
    gload16(Agp + (o0) + (size_t)(koff), (dst) + tid * 16);                 \
    gload16(Agp + (o1) + (size_t)(koff), (dst) + 8192 + tid * 16);          \
} while (0)
#define STG_B(dst, koff) do {                                               \
    gload16(Bgp + boffB0 + (size_t)(koff), (dst) + tid * 16);               \
    gload16(Bgp + boffB1 + (size_t)(koff), (dst) + 8192 + tid * 16);        \
} while (0)
#define STAGE_TILE(c, koff) do {                                            \
    STG_A(LDS_A(c, 0), aoff00, aoff01, (koff));                             \
    STG_A(LDS_A(c, 1), aoff10, aoff11, (koff));                             \
    STG_B(LDS_B(c, 0), (koff));                                             \
    STG_B(LDS_B(c, 1), (koff) + 32);                                        \
} while (0)

#define LOAD_AV(dst, c, mq, kk) do {                                        \
    const char* ab = LDS_A(c, wm);                                          \
    _Pragma("unroll") for (int i = 0; i < 4; ++i) {                         \
        int rr = (mq) * 64 + i * 16 + (lane & 15);                          \
        int sl = ((kk) * 4 + (lane >> 4)) ^ (rr & 7);                       \
        dst[i] = *(const s16x8*)(ab + rr * 128 + sl * 16);                  \
    }                                                                       \
} while (0)
#define LOAD_BV(dst, c, kk) do {                                            \
    const char* bb = LDS_B(c, kk);                                          \
    _Pragma("unroll") for (int nf = 0; nf < 4; ++nf) {                      \
        int rb = wn * 64 + nf * 16 + (lane & 15);                           \
        int sl = (lane >> 4) ^ ((rb >> 1) & 3);                             \
        dst[nf] = *(const s16x8*)(bb + rb * 64 + sl * 16);                  \
    }                                                                       \
} while (0)
#define MFMA16(base, A_, B_) do {                                           \
    _Pragma("unroll") for (int i = 0; i < 4; ++i)                           \
    _Pragma("unroll") for (int nf = 0; nf < 4; ++nf)                        \
        acc[(base) * 4 + i][nf] = __builtin_amdgcn_mfma_f32_16x16x32_bf16(  \
            A_[i], B_[nf], acc[(base) * 4 + i][nf], 0, 0, 0);               \
} while (0)
#define COMPUTE_TILE(c) do {                                                \
    s16x8 av0[4], av1[4], av2[4], av3[4], bv0[4], bv1[4];                   \
    LOAD_AV(av0, c, 0, 0); LOAD_BV(bv0, c, 0);                              \
    LOAD_AV(av1, c, 1, 0);                                                  \
    MFMA16(0, av0, bv0);                                                    \
    LOAD_AV(av2, c, 0, 1); LOAD_BV(bv1, c, 1);                              \
    MFMA16(1, av1, bv0);                                                    \
    LOAD_AV(av3, c, 1, 1);                                                  \
    MFMA16(0, av2, bv1);                                                    \
    MFMA16(1, av3, bv1);                                                    \
} while (0)

#define PIPE2(NT, KBASE) do {                                               \
    STAGE_TILE(0, (size_t)(KBASE));                                         \
    STAGE_TILE(1, (size_t)(KBASE) + BK);                                    \
    _Pragma("unroll 1")                                                     \
    for (int t = 0; t < (NT); t += 2) {                                     \
        VM8(); BARX();                                                      \
        COMPUTE_TILE(0);                                                    \
        BARX();                                                             \
        if (t + 2 < (NT)) {                                                 \
            STAGE_TILE(0, (size_t)(KBASE) + (size_t)(t + 2) * BK);          \
            VM8();                                                          \
        } else { VM0(); }                                                   \
        BARX();                                                             \
        COMPUTE_TILE(1);                                                    \
        BARX();                                                             \
        if (t + 3 < (NT))                                                   \
            STAGE_TILE(1, (size_t)(KBASE) + (size_t)(t + 3) * BK);          \
    }                                                                       \
} while (0)

#define B_STAGE_OFFS(basecol, ldb) \
    int rB0 = tid >> 2,         sB0 = (tid & 3) ^ ((rB0 >> 1) & 3);         \
    int rB1 = (512 + tid) >> 2, sB1 = ((512 + tid) & 3) ^ ((rB1 >> 1) & 3); \
    size_t boffB0 = ((size_t)(basecol) + rB0) * (ldb) + sB0 * 8;            \
    size_t boffB1 = ((size_t)(basecol) + rB1) * (ldb) + sB1 * 8;

// GEMM1: H1[p, n] = gelu( sum_d xb[tok[p], d] * W1b[e, n, d] + b1[e, n] )
// XCD-pinned: g=bid&7 -> colb in {2g, 2g+1}; idx=bid>>3 tile-major.
// Each XCD keeps its two 0.5 MB W1 panels (per expert) L2-resident; the two
// colb blocks of a tile are adjacent bids -> concurrent -> A slab L2-shared.
__global__ __launch_bounds__(512, 2) void gemm1_kernel(
    const u16* __restrict__ xb, const u16* __restrict__ W1b, const float* __restrict__ b1,
    const int* __restrict__ tok, const int* __restrict__ cnt, const int* __restrict__ offs,
    const u32* __restrict__ table, const int* __restrict__ meta,
    u16* __restrict__ H1, int p0, int p1)
{
    int nt = meta[0];
    int g = blockIdx.x & 7;
    int idx = blockIdx.x >> 3;
    if (idx >= 2 * nt) return;
    int tile = idx >> 1;
    int colb = g * 2 + (idx & 1);              // [0,16)
    u32 entry = table[tile];
    const int e = (int)(entry >> 20);
    const int row0 = (int)(entry & 0xFFFFFu);
    const int ce = cnt[e], oe = offs[e];
    if (oe + min(ce, row0 + BM) <= p0 || oe + row0 >= p1) return;
    const int col0 = colb * BN;

    __shared__ __align__(16) u16 S[65536];     // 128 KiB

    const int tid = threadIdx.x;               // 0..511
    const int lane = tid & 63, wid = tid >> 6;
    const int wm = wid >> 2, wn = wid & 3;     // 2x4 wave grid; wave C = 128x64

    f32x4 acc[8][4] = {};

    const u16* Agp = xb;
    const u16* Bgp = W1b;
    int r0c = tid >> 3,        s0 = (tid & 7) ^ (r0c & 7);
    int r1c = 64 + (tid >> 3), s1 = (tid & 7) ^ (r1c & 7);
#define TOKA(h, rc) ((row0 + (h) * 128 + (rc)) < ce ? tok[oe + row0 + (h) * 128 + (rc)] : tok[oe])
    size_t aoff00 = (size_t)TOKA(0, r0c) * DMODEL + s0 * 8;
    size_t aoff01 = (size_t)TOKA(0, r1c) * DMODEL + s1 * 8;
    size_t aoff10 = (size_t)TOKA(1, r0c) * DMODEL + s0 * 8;
    size_t aoff11 = (size_t)TOKA(1, r1c) * DMODEL + s1 * 8;
#undef TOKA
    B_STAGE_OFFS((size_t)e * HID + col0, DMODEL)

    PIPE2(DMODEL / BK, 0);                     // 16 K-tiles

    float bias[4];
#pragma unroll
    for (int nf = 0; nf < 4; ++nf)
        bias[nf] = b1[e * HID + col0 + wn * 64 + nf * 16 + (lane & 15)];

#pragma unroll
    for (int mf = 0; mf < 8; ++mf) {
#pragma unroll
        for (int j = 0; j < 4; ++j) {
            int r = wm * 128 + mf * 16 + ((lane >> 4) * 4) + j;
            int gi = row0 + r;
            int p = oe + gi;
            if (gi < ce && p >= p0 && p < p1) {
                u16* hrow = H1 + (size_t)(p - p0) * HID;
#pragma unroll
                for (int nf = 0; nf < 4; ++nf) {
                    int n = col0 + wn * 64 + nf * 16 + (lane & 15);
                    hrow[n] = f2b(gelu_fast(acc[mf][nf][j] + bias[nf]));
                }
            }
        }
    }
}

// ================= gemm2: 128x256 core, XCD-pinned column groups ============
// LDS per buffer c (48 KiB): A 128x64 (128B rows, slot^(row&7)) at c*48K,
// B 256x64 (same format) at c*48K + 16K. dbuf = 96 KiB.
#define LDS_A2(c) ((char*)S2 + (c) * 49152)
#define LDS_B2(c) ((char*)S2 + (c) * 49152 + 16384)

#define STAGE_TILE2(c, koff) do {                                           \
    gload16(Agp + aoffA0 + (size_t)(koff), LDS_A2(c) + tid * 16);           \
    gload16(Agp + aoffA1 + (size_t)(koff), LDS_A2(c) + 8192 + tid * 16);    \
    gload16(Bgp + boffB0 + (size_t)(koff), LDS_B2(c) + tid * 16);           \
    gload16(Bgp + boffB1 + (size_t)(koff), LDS_B2(c) + 8192 + tid * 16);    \
    gload16(Bgp + boffB2 + (size_t)(koff), LDS_B2(c) + 16384 + tid * 16);   \
    gload16(Bgp + boffB3 + (size_t)(koff), LDS_B2(c) + 24576 + tid * 16);   \
} while (0)

#define LOAD_AV2(dst, c, kk) do {                                           \
    const char* ab = LDS_A2(c);                                             \
    _Pragma("unroll") for (int i = 0; i < 4; ++i) {                         \
        int rr = wm * 64 + i * 16 + (lane & 15);                            \
        int sl = ((kk) * 4 + (lane >> 4)) ^ (rr & 7);                       \
        dst[i] = *(const s16x8*)(ab + rr * 128 + sl * 16);                  \
    }                                                                       \
} while (0)
#define LOAD_BV2(dst, c, kk) do {                                           \
    const char* bb = LDS_B2(c);                                             \
    _Pragma("unroll") for (int nf = 0; nf < 4; ++nf) {                      \
        int rb = wn * 64 + nf * 16 + (lane & 15);                           \
        int sl = ((kk) * 4 + (lane >> 4)) ^ (rb & 7);                       \
        dst[nf] = *(const s16x8*)(bb + rb * 128 + sl * 16);                 \
    }                                                                       \
} while (0)
#define MFMA_ALL2(A_, B_) do {                                              \
    _Pragma("unroll") for (int i = 0; i < 4; ++i)                           \
    _Pragma("unroll") for (int nf = 0; nf < 4; ++nf)                        \
        acc[i][nf] = __builtin_amdgcn_mfma_f32_16x16x32_bf16(               \
            A_[i], B_[nf], acc[i][nf], 0, 0, 0);                            \
} while (0)
#define COMPUTE_TILE2(c) do {                                               \
    s16x8 av0[4], av1[4], bv0[4], bv1[4];                                   \
    LOAD_AV2(av0, c, 0); LOAD_BV2(bv0, c, 0);                               \
    LOAD_AV2(av1, c, 1);                                                    \
    MFMA_ALL2(av0, bv0);                                                    \
    LOAD_BV2(bv1, c, 1);                                                    \
    MFMA_ALL2(av1, bv1);                                                    \
} while (0)

#define PIPE2B(NT, KBASE) do {                                              \
    STAGE_TILE2(0, (size_t)(KBASE));                                        \
    STAGE_TILE2(1, (size_t)(KBASE) + BK);                                   \
    _Pragma("unroll 1")                                                     \
    for (int t = 0; t < (NT); t += 2) {                                     \
        VM6(); BARX();                                                      \
        COMPUTE_TILE2(0);                                                   \
        BARX();                                                             \
        if (t + 2 < (NT)) {                                                 \
            STAGE_TILE2(0, (size_t)(KBASE) + (size_t)(t + 2) * BK);         \
            VM6();                                                          \
        } else { VM0(); }                                                   \
        BARX();                                                             \
        COMPUTE_TILE2(1);                                                   \
        BARX();                                                             \
        if (t + 3 < (NT))                                                   \
            STAGE_TILE2(1, (size_t)(KBASE) + (size_t)(t + 3) * BK);         \
    }                                                                       \
} while (0)

// GEMM2 (K-split x2): out[tok[p], d] += wgt[p]*(sum_h H1[p,h]*W2b[e,d,h] + b2[e,d])
// g=bid&7 pins (colb,khalf) to one XCD: B panel (1 MB) L2-resident; H1 slabs
// stream through L3 exactly once per XCD. tix=bid>>3 over 128-row tiles.
__global__ __launch_bounds__(512, 2) void gemm2_kernel(
    const u16* __restrict__ H1, const u16* __restrict__ W2b, const float* __restrict__ b2,
    const int* __restrict__ tok, const float* __restrict__ wgt,
    const int* __restrict__ cnt, const int* __restrict__ offs,
    const u32* __restrict__ table2, const int* __restrict__ meta,
    float* __restrict__ out, int p0, int p1)
{
    int nt2 = meta[1];
    int g = blockIdx.x & 7;
    int tix = blockIdx.x >> 3;
    if (tix >= nt2) return;
    int colb = g >> 1, khalf = g & 1;
    u32 entry = table2[tix];
    const int e = (int)(entry >> 20);
    const int row0 = (int)(entry & 0xFFFFFu);
    const int ce = cnt[e], oe = offs[e];
    if (oe + min(ce, row0 + 128) <= p0 || oe + row0 >= p1) return;
    const int col0 = colb * BN;
    const int kbase = khalf * (HID / 2);

    __shared__ __align__(16) u16 S2[49152];    // 96 KiB

    const int tid = threadIdx.x;
    const int lane = tid & 63, wid = tid >> 6;
    const int wm = wid >> 2, wn = wid & 3;     // 2x4 waves; wave C = 64x64

    f32x4 acc[4][4] = {};

    const u16* Agp = H1;
    const u16* Bgp = W2b;
    const int smax = p1 - p0 - 1;
    // A: 1024 chunks (128 rows x 8 slots), 2 per thread
    int rA0 = tid >> 3,          sA0 = (tid & 7) ^ (rA0 & 7);
    int rA1 = (512 + tid) >> 3,  sA1 = (tid & 7) ^ (rA1 & 7);
#define AIDX(rc) ({ int ai_ = oe + row0 + (rc) - p0;                         \
                    ai_ < 0 ? 0 : (ai_ > smax ? smax : ai_); })
    size_t aoffA0 = (size_t)AIDX(rA0) * HID + sA0 * 8 + kbase;
    size_t aoffA1 = (size_t)AIDX(rA1) * HID + sA1 * 8 + kbase;
#undef AIDX
    // B: 2048 chunks (256 rows x 8 slots), 4 per thread
    size_t boffB0, boffB1, boffB2, boffB3;
    {
        int r0 = tid >> 3,          ss0 = (tid & 7) ^ (r0 & 7);
        int r1 = (512 + tid) >> 3,  ss1 = (tid & 7) ^ (r1 & 7);
        int r2 = (1024 + tid) >> 3, ss2 = (tid & 7) ^ (r2 & 7);
        int r3 = (1536 + tid) >> 3, ss3 = (tid & 7) ^ (r3 & 7);
        boffB0 = ((size_t)e * DMODEL + col0 + r0) * HID + ss0 * 8 + kbase;
        boffB1 = ((size_t)e * DMODEL + col0 + r1) * HID + ss1 * 8 + kbase;
        boffB2 = ((size_t)e * DMODEL + col0 + r2) * HID + ss2 * 8 + kbase;
        boffB3 = ((size_t)e * DMODEL + col0 + r3) * HID + ss3 * 8 + kbase;
    }

    PIPE2B(HID / 2 / BK, 0);                   // 32 K-tiles of the khalf

    float bias[4];
#pragma unroll
    for (int nf = 0; nf < 4; ++nf)
        bias[nf] = (khalf == 0)
            ? b2[e * DMODEL + col0 + wn * 64 + nf * 16 + (lane & 15)] : 0.0f;

#pragma unroll
    for (int mf = 0; mf < 4; ++mf) {
#pragma unroll
        for (int j = 0; j < 4; ++j) {
            int r = wm * 64 + mf * 16 + ((lane >> 4) * 4) + j;
            int gi = row0 + r;
            int p = oe + gi;
            if (gi < ce && p >= p0 && p < p1) {
                float w = wgt[p];
                float* orow = out + (size_t)tok[p] * DMODEL;
#pragma unroll
                for (int nf = 0; nf < 4; ++nf) {
                    int n = col0 + wn * 64 + nf * 16 + (lane & 15);
                    atomicAdd(orow + n, w * (acc[mf][nf][j] + bias[nf]));
                }
            }
        }
    }
}

// ---------------- host launcher ----------------
extern "C" void kernel_launch(void* const* d_in, const int* in_sizes, int n_in,
                              void* d_out, int out_size, void* d_ws, size_t ws_size,
                              hipStream_t stream)
{
    const float* x  = (const float*)d_in[0];
    const float* Wr = (const float*)d_in[1];
    const float* br = (const float*)d_in[2];
    const float* W1 = (const float*)d_in[3];
    const float* b1 = (const float*)d_in[4];
    const float* W2 = (const float*)d_in[5];
    const float* b2 = (const float*)d_in[6];
    float* out = (float*)d_out;

    char* ws = (char*)d_ws;
    u16* xb = (u16*)ws;                               // 16 MiB
    size_t o2 = (size_t)T_TOK * DMODEL * 2;
    int*   cnt    = (int*)(ws + o2);
    int*   fill   = (int*)(ws + o2 + 64);
    int*   offs   = (int*)(ws + o2 + 128);
    int*   meta   = (int*)(ws + o2 + 192);
    u32*   table  = (u32*)(ws + o2 + 256);            // <=72 entries
    u32*   table2 = (u32*)(ws + o2 + 1024);           // <=136 entries
    int*   topi   = (int*)(ws + o2 + 2048);
    float* topw   = (float*)(ws + o2 + 2048 + (size_t)NPAIR * 4);
    int*   tok    = (int*)(ws + o2 + 2048 + (size_t)NPAIR * 8);
    float* wgt    = (float*)(ws + o2 + 2048 + (size_t)NPAIR * 12);

    const size_t WBYTES = (size_t)NEXP * DMODEL * HID * 2;   // 64 MiB each
    size_t oW2 = o2 + (2u << 20);
    size_t oW1 = oW2 + WBYTES;
    size_t oH  = oW1 + WBYTES;
    u16* W2b = (u16*)(ws + oW2);
    u16* W1b = (u16*)(ws + oW1);
    u16* H1  = (u16*)(ws + oH);

    long long cap = ((long long)ws_size - (long long)oH) / ((long long)HID * 2);
    int slice = cap >= NPAIR ? NPAIR : (cap < 1024 ? 1024 : (int)cap);

    hipMemsetAsync(out, 0, (size_t)out_size * 4, stream);
    hipMemsetAsync(cnt, 0, 256, stream);

    cvt_kernel<<<dim3(1024), 256, 0, stream>>>(x, xb, (long)T_TOK * DMODEL / 8);
    cvt_kernel<<<dim3(4096), 256, 0, stream>>>(W2, W2b, (long)NEXP * DMODEL * HID / 8);
    cvt_kernel<<<dim3(4096), 256, 0, stream>>>(W1, W1b, (long)NEXP * DMODEL * HID / 8);

    router_kernel<<<dim3(T_TOK / 4), 256, 0, stream>>>(x, Wr, br, topi, topw, cnt);
    offsets_kernel<<<dim3(1), 64, 0, stream>>>(cnt, offs, table, table2, meta);
    scatter_kernel<<<dim3(T_TOK / 256), 256, 0, stream>>>(topi, topw, offs, fill, tok, wgt);

    for (int pp = 0; pp < NPAIR; pp += slice) {
        int p1v = pp + slice < NPAIR ? pp + slice : NPAIR;
        gemm1_kernel<<<dim3(16 * MAXT), 512, 0, stream>>>(
            xb, W1b, b1, tok, cnt, offs, table, meta, H1, pp, p1v);
        gemm2_kernel<<<dim3(8 * MAXT2), 512, 0, stream>>>(
            H1, W2b, b2, tok, wgt, cnt, offs, table2, meta, out, pp, p1v);
    }
}

// Round 11
// 756.174 us; speedup vs baseline: 1.0115x; 1.0115x over previous
//
#include <hip/hip_runtime.h>

// ---- problem dims (fixed) ----
#define T_TOK 8192      // B*S
#define DMODEL 1024
#define NEXP 8
#define TOPK 2
#define HID 4096
#define NPAIR (T_TOK*TOPK)   // 16384
#define BM 256
#define BN 256
#define BK 64
#define MAXT (NPAIR/BM + NEXP)   // 72 row-tiles upper bound

typedef unsigned short u16;
typedef unsigned int u32;
typedef short s16x8 __attribute__((ext_vector_type(8)));
typedef float f32x4 __attribute__((ext_vector_type(4)));

// fp32 -> bf16 round-to-nearest-even
__device__ __forceinline__ u16 f2b(float f) {
    union { float f; unsigned int u; } v; v.f = f;
    return (u16)((v.u + 0x7fffu + ((v.u >> 16) & 1u)) >> 16);
}

__device__ __forceinline__ s16x8 cvt8(float4 f0, float4 f1) {
    s16x8 o;
    o[0]=(short)f2b(f0.x); o[1]=(short)f2b(f0.y); o[2]=(short)f2b(f0.z); o[3]=(short)f2b(f0.w);
    o[4]=(short)f2b(f1.x); o[5]=(short)f2b(f1.y); o[6]=(short)f2b(f1.z); o[7]=(short)f2b(f1.w);
    return o;
}

// async global->LDS, 16B per lane; LDS dest linear in lane order
__device__ __forceinline__ void gload16(const void* g, void* l) {
    __builtin_amdgcn_global_load_lds(
        (const __attribute__((address_space(1))) unsigned int*)g,
        (__attribute__((address_space(3))) unsigned int*)l, 16, 0, 0);
}

// tanh-form gelu, exp/rcp in HW
__device__ __forceinline__ float gelu_fast(float v) {
    float y = 0.7978845608028654f * v * fmaf(0.044715f * v, v, 1.0f);
    float t = -2.8853900817779268f * y;   // -2y * log2(e)
    float z, r;
    asm("v_exp_f32 %0, %1" : "=v"(z) : "v"(t));
    float den = 1.0f + z;
    asm("v_rcp_f32 %0, %1" : "=v"(r) : "v"(den));
    return v * r;
}

// m204 bijective XCD swizzle over nact active blocks
__device__ __forceinline__ int xcd_swz(int bid, int nact) {
    int q = nact >> 3, r = nact & 7;
    int xcd = bid & 7, i = bid >> 3;
    return (xcd < r ? xcd * (q + 1) : r * (q + 1) + (xcd - r) * q) + i;
}

// ---------------- fp32 -> bf16 conversion ----------------
__global__ __launch_bounds__(256) void cvt_kernel(const float* __restrict__ in,
                                                  u16* __restrict__ out, long n8) {
    long stride = (long)gridDim.x * 256;
    for (long i = (long)blockIdx.x * 256 + threadIdx.x; i < n8; i += stride) {
        const float4* p = (const float4*)(in + i * 8);
        float4 f0 = p[0], f1 = p[1];
        *(s16x8*)(out + i * 8) = cvt8(f0, f1);
    }
}

// ---------------- router (fp32; selection must match reference) ----------------
__global__ __launch_bounds__(256) void router_kernel(
    const float* __restrict__ x, const float* __restrict__ Wr, const float* __restrict__ br,
    int* __restrict__ topi, float* __restrict__ topw, int* __restrict__ cnt)
{
    __shared__ float WrS[NEXP * DMODEL];
    int tid = threadIdx.x;
    const float4* Wr4 = (const float4*)Wr;
    float4* WrS4 = (float4*)WrS;
    for (int i = tid; i < NEXP * DMODEL / 4; i += 256) WrS4[i] = Wr4[i];
    __syncthreads();

    int wid = tid >> 6, lane = tid & 63;
    int t = blockIdx.x * 4 + wid;
    const float* xr = x + (size_t)t * DMODEL;

    float acc[NEXP];
#pragma unroll
    for (int e = 0; e < NEXP; ++e) acc[e] = 0.f;
    for (int i = lane; i < DMODEL; i += 64) {
        float xv = xr[i];
#pragma unroll
        for (int e = 0; e < NEXP; ++e) acc[e] = fmaf(xv, WrS[e * DMODEL + i], acc[e]);
    }
#pragma unroll
    for (int e = 0; e < NEXP; ++e) {
        float v = acc[e];
#pragma unroll
        for (int off = 32; off > 0; off >>= 1) v += __shfl_xor(v, off);
        acc[e] = v;
    }
    if (lane == 0) {
        float lg[NEXP];
#pragma unroll
        for (int e = 0; e < NEXP; ++e) lg[e] = acc[e] + br[e];
        int i1 = 0;
#pragma unroll
        for (int e = 1; e < NEXP; ++e) if (lg[e] > lg[i1]) i1 = e;
        int i2 = (i1 == 0) ? 1 : 0;
#pragma unroll
        for (int e = 0; e < NEXP; ++e) if (e != i1 && lg[e] > lg[i2]) i2 = e;
        float e2 = expf(lg[i2] - lg[i1]);
        float s = 1.f + e2;
        topi[t * 2] = i1;  topi[t * 2 + 1] = i2;
        topw[t * 2] = 1.f / s;  topw[t * 2 + 1] = e2 / s;
        atomicAdd(&cnt[i1], 1);
        atomicAdd(&cnt[i2], 1);
    }
}

// offsets + compact tile table (BM=256) + tile count
__global__ void offsets_kernel(const int* __restrict__ cnt, int* __restrict__ offs,
                               u32* __restrict__ table, int* __restrict__ meta) {
    if (threadIdx.x == 0 && blockIdx.x == 0) {
        int a = 0;
        for (int e = 0; e < NEXP; ++e) { offs[e] = a; a += cnt[e]; }
        offs[NEXP] = a;
        int nt = 0;
        for (int e = 0; e < NEXP; ++e)
            for (int r0 = 0; r0 < cnt[e]; r0 += BM)
                table[nt++] = ((u32)e << 20) | (u32)r0;
        meta[0] = nt;
    }
}

// wave-aggregated scatter
__global__ __launch_bounds__(256) void scatter_kernel(
    const int* __restrict__ topi, const float* __restrict__ topw,
    const int* __restrict__ offs, int* __restrict__ fill,
    int* __restrict__ tok, float* __restrict__ wgt)
{
    int t = blockIdx.x * 256 + threadIdx.x;
    int lane = threadIdx.x & 63;
#pragma unroll
    for (int s = 0; s < TOPK; ++s) {
        int e = topi[t * 2 + s];
        float w = topw[t * 2 + s];
#pragma unroll
        for (int ex = 0; ex < NEXP; ++ex) {
            unsigned long long m = __ballot(e == ex);
            if (e == ex) {
                int ldr = (int)__ffsll((unsigned long long)m) - 1;
                int base = 0;
                if (lane == ldr) base = atomicAdd(&fill[ex], (int)__popcll(m));
                base = __shfl(base, ldr);
                int mypos = base + (int)__popcll(m & ((1ull << lane) - 1ull));
                int p = offs[ex] + mypos;
                tok[p] = t;
                wgt[p] = w;
            }
        }
    }
}

// ======== 256x256 8-phase counted-vmcnt GEMM engine ========
// LDS 128 KiB, buffer c in {0,1} COMPILE-TIME (even K-tiles->buf0, odd->buf1):
//   A half h (128 rows x 64 k, 128B rows, slot^(row&7) swizzle) at c*64K + h*16K
//   Bk kk  (256 rows x 32 k,  64B rows, slot = g^((row>>1)&3))  at c*64K + 32K + kk*16K
#define LDS_A(c, h)  ((char*)S + (c) * 65536 + (h) * 16384)
#define LDS_B(c, kk) ((char*)S + (c) * 65536 + 32768 + (kk) * 16384)

#define STG_A(dst, o0, o1, koff) do {                                       \
    gload16(Agp + (o0) + (size_t)(koff), (dst) + tid * 16);                 \
    gload16(Agp + (o1) + (size_t)(koff), (dst) + 8192 + tid * 16);          \
} while (0)
#define STG_B(dst, koff) do {                                               \
    gload16(Bgp + boffB0 + (size_t)(koff), (dst) + tid * 16);               \
    gload16(Bgp + boffB1 + (size_t)(koff), (dst) + 8192 + tid * 16);        \
} while (0)

#define LOAD_AV(c, mq, kk) do {                                             \
    const char* ab = LDS_A(c, wm);                                          \
    _Pragma("unroll") for (int i = 0; i < 4; ++i) {                         \
        int rr = (mq) * 64 + i * 16 + (lane & 15);                          \
        int sl = ((kk) * 4 + (lane >> 4)) ^ (rr & 7);                       \
        av[i] = *(const s16x8*)(ab + rr * 128 + sl * 16);                   \
    }                                                                       \
} while (0)
#define LOAD_BV(c, kk) do {                                                 \
    const char* bb = LDS_B(c, kk);                                          \
    _Pragma("unroll") for (int nf = 0; nf < 4; ++nf) {                      \
        int rb = wn * 64 + nf * 16 + (lane & 15);                           \
        int sl = (lane >> 4) ^ ((rb >> 1) & 3);                             \
        bv[nf] = *(const s16x8*)(bb + rb * 64 + sl * 16);                   \
    }                                                                       \
} while (0)

#define MFMA_PH(mq) do {                                                    \
    __builtin_amdgcn_s_setprio(1);                                          \
    _Pragma("unroll") for (int i = 0; i < 4; ++i)                           \
    _Pragma("unroll") for (int nf = 0; nf < 4; ++nf)                        \
        acc[(mq) * 4 + i][nf] = __builtin_amdgcn_mfma_f32_16x16x32_bf16(    \
            av[i], bv[nf], acc[(mq) * 4 + i][nf], 0, 0, 0);                 \
    __builtin_amdgcn_s_setprio(0);                                          \
} while (0)

#define VMW(n) asm volatile("s_waitcnt vmcnt(" #n ")" ::: "memory")
// barrier #1: pin read/stage issue above; then force own ds_reads drained and
// keep MFMAs below the wait (rule #18: sched_barrier after inline-asm lgkmcnt)
#define PH_BAR1() do {                                                      \
    __builtin_amdgcn_sched_barrier(0);                                      \
    __builtin_amdgcn_s_barrier();                                           \
    asm volatile("s_waitcnt lgkmcnt(0)" ::: "memory");                      \
    __builtin_amdgcn_sched_barrier(0);                                      \
} while (0)
#define PH_BAR2() do {                                                      \
    __builtin_amdgcn_sched_barrier(0);                                      \
    __builtin_amdgcn_s_barrier();                                           \
} while (0)

// One iteration = K-tiles t (buf0, P1-4) and t+1 (buf1, P5-8).
// Stages: P1/P2: buf1.A0/A1 (tile t+1), P3/P4: buf1.Bk0/Bk1,
//         P5/P6: buf0.A0/A1 (tile t+2), P7/P8: buf0.Bk0/Bk1.
// Counted waits (per-wave queue arithmetic, 2 loads/stage):
//   end-P2: vmcnt(4) -> prev-P8 Bk1 landed (used P3)
//   end-P4: vmcnt(2) -> P1,P2,P3 landed (used P5)
//   end-P6: vmcnt(4) -> P4 Bk1 landed (used P7)   [last iter: vmcnt(0)]
//   end-P8: vmcnt(2) -> P5,P6,P7 landed (used next P1)
#define ITER8(kt, last) do {                                                \
    /* P1 */                                                                \
    LOAD_AV(0, 0, 0); LOAD_BV(0, 0);                                        \
    STG_A(LDS_A(1, 0), aoff00, aoff01, (kt) + BK);                          \
    PH_BAR1(); MFMA_PH(0); PH_BAR2();                                       \
    /* P2 */                                                                \
    LOAD_AV(0, 1, 0);                                                       \
    STG_A(LDS_A(1, 1), aoff10, aoff11, (kt) + BK);                          \
    PH_BAR1(); MFMA_PH(1); VMW(4); PH_BAR2();                               \
    /* P3 */                                                                \
    LOAD_AV(0, 0, 1); LOAD_BV(0, 1);                                        \
    STG_B(LDS_B(1, 0), (kt) + BK);                                          \
    PH_BAR1(); MFMA_PH(0); PH_BAR2();                                       \
    /* P4 */                                                                \
    LOAD_AV(0, 1, 1);                                                       \
    STG_B(LDS_B(1, 1), (kt) + BK + 32);                                     \
    PH_BAR1(); MFMA_PH(1); VMW(2); PH_BAR2();                               \
    /* P5 */                                                                \
    LOAD_AV(1, 0, 0); LOAD_BV(1, 0);                                        \
    if (!(last)) STG_A(LDS_A(0, 0), aoff00, aoff01, (kt) + 2 * BK);         \
    PH_BAR1(); MFMA_PH(0); PH_BAR2();                                       \
    /* P6 */                                                                \
    LOAD_AV(1, 1, 0);                                                       \
    if (!(last)) STG_A(LDS_A(0, 1), aoff10, aoff11, (kt) + 2 * BK);         \
    PH_BAR1(); MFMA_PH(1);                                                  \
    if (last) { VMW(0); } else { VMW(4); }                                  \
    PH_BAR2();                                                              \
    /* P7 */                                                                \
    LOAD_AV(1, 0, 1); LOAD_BV(1, 1);                                        \
    if (!(last)) STG_B(LDS_B(0, 0), (kt) + 2 * BK);                         \
    PH_BAR1(); MFMA_PH(0); PH_BAR2();                                       \
    /* P8 */                                                                \
    LOAD_AV(1, 1, 1);                                                       \
    if (!(last)) STG_B(LDS_B(0, 1), (kt) + 2 * BK + 32);                    \
    PH_BAR1(); MFMA_PH(1);                                                  \
    if (!(last)) { VMW(2); }                                                \
    PH_BAR2();                                                              \
} while (0)

// prologue: stage tile 0 into buf0; Bk1 allowed in flight (covered by P2 wait)
#define PIPE8(NT, KBASE) do {                                               \
    { size_t k0 = (size_t)(KBASE);                                          \
      STG_A(LDS_A(0, 0), aoff00, aoff01, k0);                               \
      STG_A(LDS_A(0, 1), aoff10, aoff11, k0);                               \
      STG_B(LDS_B(0, 0), k0);                                               \
      STG_B(LDS_B(0, 1), k0 + 32); }                                        \
    VMW(2); __builtin_amdgcn_s_barrier();                                   \
    _Pragma("unroll 1")                                                     \
    for (int t = 0; t < (NT); t += 2) {                                     \
        const bool last = (t + 2 >= (NT));                                  \
        ITER8((size_t)(KBASE) + (size_t)t * BK, last);                      \
    }                                                                       \
} while (0)

#define B_STAGE_OFFS(basecol, ldb) \
    int rB0 = tid >> 2,         sB0 = (tid & 3) ^ ((rB0 >> 1) & 3);         \
    int rB1 = (512 + tid) >> 2, sB1 = ((512 + tid) & 3) ^ ((rB1 >> 1) & 3); \
    size_t boffB0 = ((size_t)(basecol) + rB0) * (ldb) + sB0 * 8;            \
    size_t boffB1 = ((size_t)(basecol) + rB1) * (ldb) + sB1 * 8;

// GEMM1: H1[p, n] = gelu( sum_d xb[tok[p], d] * W1b[e, n, d] + b1[e, n] )
__global__ __launch_bounds__(512, 2) void gemm1_kernel(
    const u16* __restrict__ xb, const u16* __restrict__ W1b, const float* __restrict__ b1,
    const int* __restrict__ tok, const int* __restrict__ cnt, const int* __restrict__ offs,
    const u32* __restrict__ table, const int* __restrict__ meta,
    u16* __restrict__ H1, int p0, int p1)
{
    const int NCOL = HID / BN;                 // 16
    int nt = meta[0];
    int nact = NCOL * nt;
    int bid = blockIdx.x;
    if (bid >= nact) return;
    int swz = xcd_swz(bid, nact);
    int tile = swz / NCOL, colb = swz & (NCOL - 1);
    u32 entry = table[tile];
    const int e = (int)(entry >> 20);
    const int row0 = (int)(entry & 0xFFFFFu);
    const int ce = cnt[e], oe = offs[e];
    if (oe + min(ce, row0 + BM) <= p0 || oe + row0 >= p1) return;
    const int col0 = colb * BN;

    __shared__ __align__(16) u16 S[65536];     // 128 KiB

    const int tid = threadIdx.x;               // 0..511
    const int lane = tid & 63, wid = tid >> 6;
    const int wm = wid >> 2, wn = wid & 3;     // 2x4 wave grid; wave C = 128x64

    f32x4 acc[8][4] = {};
    s16x8 av[4], bv[4];

    const u16* Agp = xb;
    const u16* Bgp = W1b;
    int r0c = tid >> 3,        s0 = (tid & 7) ^ (r0c & 7);
    int r1c = 64 + (tid >> 3), s1 = (tid & 7) ^ (r1c & 7);
#define TOKA(h, rc) ((row0 + (h) * 128 + (rc)) < ce ? tok[oe + row0 + (h) * 128 + (rc)] : tok[oe])
    size_t aoff00 = (size_t)TOKA(0, r0c) * DMODEL + s0 * 8;
    size_t aoff01 = (size_t)TOKA(0, r1c) * DMODEL + s1 * 8;
    size_t aoff10 = (size_t)TOKA(1, r0c) * DMODEL + s0 * 8;
    size_t aoff11 = (size_t)TOKA(1, r1c) * DMODEL + s1 * 8;
#undef TOKA
    B_STAGE_OFFS((size_t)e * HID + col0, DMODEL)

    PIPE8(DMODEL / BK, 0);                     // 16 K-tiles, 8 iterations

    float bias[4];
#pragma unroll
    for (int nf = 0; nf < 4; ++nf)
        bias[nf] = b1[e * HID + col0 + wn * 64 + nf * 16 + (lane & 15)];

#pragma unroll
    for (int mf = 0; mf < 8; ++mf) {
#pragma unroll
        for (int j = 0; j < 4; ++j) {
            int r = wm * 128 + mf * 16 + ((lane >> 4) * 4) + j;
            int gi = row0 + r;
            int p = oe + gi;
            if (gi < ce && p >= p0 && p < p1) {
                u16* hrow = H1 + (size_t)(p - p0) * HID;
#pragma unroll
                for (int nf = 0; nf < 4; ++nf) {
                    int n = col0 + wn * 64 + nf * 16 + (lane & 15);
                    hrow[n] = f2b(gelu_fast(acc[mf][nf][j] + bias[nf]));
                }
            }
        }
    }
}

// GEMM2 (K-split x2): out[tok[p], d] += wgt[p]*(sum_h H1[p,h]*W2b[e,d,h] + b2[e,d])
__global__ __launch_bounds__(512, 2) void gemm2_kernel(
    const u16* __restrict__ H1, const u16* __restrict__ W2b, const float* __restrict__ b2,
    const int* __restrict__ tok, const float* __restrict__ wgt,
    const int* __restrict__ cnt, const int* __restrict__ offs,
    const u32* __restrict__ table, const int* __restrict__ meta,
    float* __restrict__ out, int p0, int p1)
{
    int nt = meta[0];
    int nact = 8 * nt;                         // 4 colb x 2 khalf
    int bid = blockIdx.x;
    if (bid >= nact) return;
    int swz = xcd_swz(bid, nact);
    int tile = swz >> 3;
    int rem = swz & 7;
    int colb = rem >> 1, khalf = rem & 1;
    u32 entry = table[tile];
    const int e = (int)(entry >> 20);
    const int row0 = (int)(entry & 0xFFFFFu);
    const int ce = cnt[e], oe = offs[e];
    if (oe + min(ce, row0 + BM) <= p0 || oe + row0 >= p1) return;
    const int col0 = colb * BN;
    const int kbase = khalf * (HID / 2);

    __shared__ __align__(16) u16 S[65536];     // 128 KiB

    const int tid = threadIdx.x;
    const int lane = tid & 63, wid = tid >> 6;
    const int wm = wid >> 2, wn = wid & 3;

    f32x4 acc[8][4] = {};
    s16x8 av[4], bv[4];

    const u16* Agp = H1;
    const u16* Bgp = W2b;
    const int smax = p1 - p0 - 1;
    int r0c = tid >> 3,        s0 = (tid & 7) ^ (r0c & 7);
    int r1c = 64 + (tid >> 3), s1 = (tid & 7) ^ (r1c & 7);
#define AIDX(h, rc) ({ int ai_ = oe + row0 + (h) * 128 + (rc) - p0;          \
                       ai_ < 0 ? 0 : (ai_ > smax ? smax : ai_); })
    size_t aoff00 = (size_t)AIDX(0, r0c) * HID + s0 * 8;
    size_t aoff01 = (size_t)AIDX(0, r1c) * HID + s1 * 8;
    size_t aoff10 = (size_t)AIDX(1, r0c) * HID + s0 * 8;
    size_t aoff11 = (size_t)AIDX(1, r1c) * HID + s1 * 8;
#undef AIDX
    B_STAGE_OFFS((size_t)e * DMODEL + col0, HID)

    PIPE8(HID / 2 / BK, kbase);                // 32 K-tiles, 16 iterations

    float bias[4];
#pragma unroll
    for (int nf = 0; nf < 4; ++nf)
        bias[nf] = (khalf == 0)
            ? b2[e * DMODEL + col0 + wn * 64 + nf * 16 + (lane & 15)] : 0.0f;

#pragma unroll
    for (int mf = 0; mf < 8; ++mf) {
#pragma unroll
        for (int j = 0; j < 4; ++j) {
            int r = wm * 128 + mf * 16 + ((lane >> 4) * 4) + j;
            int gi = row0 + r;
            int p = oe + gi;
            if (gi < ce && p >= p0 && p < p1) {
                float w = wgt[p];
                float* orow = out + (size_t)tok[p] * DMODEL;
#pragma unroll
                for (int nf = 0; nf < 4; ++nf) {
                    int n = col0 + wn * 64 + nf * 16 + (lane & 15);
                    atomicAdd(orow + n, w * (acc[mf][nf][j] + bias[nf]));
                }
            }
        }
    }
}

// ---------------- host launcher ----------------
extern "C" void kernel_launch(void* const* d_in, const int* in_sizes, int n_in,
                              void* d_out, int out_size, void* d_ws, size_t ws_size,
                              hipStream_t stream)
{
    const float* x  = (const float*)d_in[0];
    const float* Wr = (const float*)d_in[1];
    const float* br = (const float*)d_in[2];
    const float* W1 = (const float*)d_in[3];
    const float* b1 = (const float*)d_in[4];
    const float* W2 = (const float*)d_in[5];
    const float* b2 = (const float*)d_in[6];
    float* out = (float*)d_out;

    char* ws = (char*)d_ws;
    u16* xb = (u16*)ws;                               // 16 MiB
    size_t o2 = (size_t)T_TOK * DMODEL * 2;
    int*   cnt   = (int*)(ws + o2);
    int*   fill  = (int*)(ws + o2 + 64);
    int*   offs  = (int*)(ws + o2 + 128);
    int*   meta  = (int*)(ws + o2 + 192);
    u32*   table = (u32*)(ws + o2 + 256);             // <=72 entries
    int*   topi  = (int*)(ws + o2 + 2048);
    float* topw  = (float*)(ws + o2 + 2048 + (size_t)NPAIR * 4);
    int*   tok   = (int*)(ws + o2 + 2048 + (size_t)NPAIR * 8);
    float* wgt   = (float*)(ws + o2 + 2048 + (size_t)NPAIR * 12);

    const size_t WBYTES = (size_t)NEXP * DMODEL * HID * 2;   // 64 MiB each
    size_t oW2 = o2 + (2u << 20);
    size_t oW1 = oW2 + WBYTES;
    size_t oH  = oW1 + WBYTES;
    u16* W2b = (u16*)(ws + oW2);
    u16* W1b = (u16*)(ws + oW1);
    u16* H1  = (u16*)(ws + oH);

    long long cap = ((long long)ws_size - (long long)oH) / ((long long)HID * 2);
    int slice = cap >= NPAIR ? NPAIR : (cap < 1024 ? 1024 : (int)cap);

    hipMemsetAsync(out, 0, (size_t)out_size * 4, stream);
    hipMemsetAsync(cnt, 0, 256, stream);

    cvt_kernel<<<dim3(1024), 256, 0, stream>>>(x, xb, (long)T_TOK * DMODEL / 8);
    cvt_kernel<<<dim3(4096), 256, 0, stream>>>(W2, W2b, (long)NEXP * DMODEL * HID / 8);
    cvt_kernel<<<dim3(4096), 256, 0, stream>>>(W1, W1b, (long)NEXP * DMODEL * HID / 8);

    router_kernel<<<dim3(T_TOK / 4), 256, 0, stream>>>(x, Wr, br, topi, topw, cnt);
    offsets_kernel<<<dim3(1), 64, 0, stream>>>(cnt, offs, table, meta);
    scatter_kernel<<<dim3(T_TOK / 256), 256, 0, stream>>>(topi, topw, offs, fill, tok, wgt);

    for (int pp = 0; pp < NPAIR; pp += slice) {
        int p1v = pp + slice < NPAIR ? pp + slice : NPAIR;
        gemm1_kernel<<<dim3((HID / BN) * MAXT), 512, 0, stream>>>(
            xb, W1b, b1, tok, cnt, offs, table, meta, H1, pp, p1v);
        gemm2_kernel<<<dim3(8 * MAXT), 512, 0, stream>>>(
            H1, W2b, b2, tok, wgt, cnt, offs, table, meta, out, pp, p1v);
    }
}